// Round 16
// baseline (60.925 us; speedup 1.0000x reference)
//
#include <hip/hip_runtime.h>
#include <hip/hip_fp16.h>

#define BB 512
#define NN 256
#define SS 128
#define MM 64
#define UNFOLDS 6

static constexpr float EPS_ = 1e-8f;
static constexpr float L2E = 1.4426950408889634f;

// ---- prep A (blocks 0..255): column-compact recurrent params, column j=bid ----
// entry (r,j): float2 { bitcast(half2{a,c}), wE with source-idx in low 8 mantissa bits }
// packed pairwise into float4 rows PC4[r>>1][j]; rows >= cnt zeroed.
// ---- prep A (blocks 256..383): dense sensory pack (SQ format) ----
__global__ __launch_bounds__(256) void prep_compact(
    const float* __restrict__ w, const float* __restrict__ sg,
    const float* __restrict__ mu, const float* __restrict__ E,
    const float* __restrict__ mask,
    const float* __restrict__ sw, const float* __restrict__ ssg,
    const float* __restrict__ smu, const float* __restrict__ sE,
    const float* __restrict__ smask,
    const float* __restrict__ iw, const float* __restrict__ ib,
    float2* __restrict__ PC2, int* __restrict__ cnt, float4* __restrict__ SQ) {
  int bid = blockIdx.x;
  int t = threadIdx.x;
  if (bid < 256) {
    int j = bid;
    int lane = t & 63, wvi = t >> 6;
    __shared__ int wtot[4];
    int g = t * NN + j;
    float m = mask[g];
    bool active = (m != 0.0f);
    float a = sg[g] * L2E;
    union { __half2 h; float f; } ac;
    ac.h = __floats2half2_rn(-a, a * mu[g]);
    float wE = w[g] * m * E[g];
    unsigned uw = (__float_as_uint(wE) & 0xFFFFFF00u) | (unsigned)t;
    unsigned long long bal = __ballot(active);
    if (lane == 63) wtot[wvi] = __popcll(bal);
    __syncthreads();
    int base = 0;
    for (int k = 0; k < wvi; ++k) base += wtot[k];
    int total = wtot[0] + wtot[1] + wtot[2] + wtot[3];
    if (active) {
      int r = base + __popcll(bal & ((1ull << lane) - 1ull));
      PC2[((r >> 1) * NN + j) * 2 + (r & 1)] = make_float2(ac.f, __uint_as_float(uw));
    }
    int zr = total + t;
    if (zr < 256) PC2[((zr >> 1) * NN + j) * 2 + (zr & 1)] = make_float2(0.f, 0.f);
    if (t == 0) cnt[j] = total;
  } else {
    int e = (bid - 256) * 256 + t;       // < SS*NN
    int s = e >> 8, j = e & 255;
    float a = ssg[e] * L2E;
    union { __half2 h; float f; } u_;
    u_.h = __floats2half2_rn(-a * iw[s], a * (smu[e] - ib[s]));
    float wE = sw[e] * smask[e] * sE[e];
    float* dst = (float*)(SQ + (s >> 1) * NN + j);
    dst[(s & 1) * 2 + 0] = u_.f;
    dst[(s & 1) * 2 + 1] = wE;
  }
}

// max over cnt, padded to multiple of 16
__global__ __launch_bounds__(256) void prep_kmax(const int* __restrict__ cnt,
                                                 int* __restrict__ kmax) {
  __shared__ int red[256];
  int t = threadIdx.x;
  red[t] = cnt[t];
  __syncthreads();
  for (int s2 = 128; s2 > 0; s2 >>= 1) {
    if (t < s2) red[t] = max(red[t], red[t + s2]);
    __syncthreads();
  }
  if (t == 0) *kmax = (red[0] + 15) & ~15;
}

// sensory: 4 gates from one float4 (2 entries, f32 wE) + float4 of x
#define GATE4(pq, vv) do { \
  union { float f; __half2 h; } _u0, _u1; \
  _u0.f = (pq).x; _u1.f = (pq).z; \
  float2 ac0 = __half22float2(_u0.h); \
  float2 ac1 = __half22float2(_u1.h); \
  float g0a = __builtin_amdgcn_rcpf(1.f + __builtin_amdgcn_exp2f(fmaf(ac0.x, (vv).x, ac0.y))); \
  float g0b = __builtin_amdgcn_rcpf(1.f + __builtin_amdgcn_exp2f(fmaf(ac0.x, (vv).y, ac0.y))); \
  float g1a = __builtin_amdgcn_rcpf(1.f + __builtin_amdgcn_exp2f(fmaf(ac1.x, (vv).z, ac1.y))); \
  float g1b = __builtin_amdgcn_rcpf(1.f + __builtin_amdgcn_exp2f(fmaf(ac1.x, (vv).w, ac1.y))); \
  n0 = fmaf((pq).y, g0a, n0); d0 = fmaf(__builtin_fabsf((pq).y), g0a, d0); \
  n1 = fmaf((pq).y, g0b, n1); d1 = fmaf(__builtin_fabsf((pq).y), g0b, d1); \
  n0 = fmaf((pq).w, g1a, n0); d0 = fmaf(__builtin_fabsf((pq).w), g1a, d0); \
  n1 = fmaf((pq).w, g1b, n1); d1 = fmaf(__builtin_fabsf((pq).w), g1b, d1); \
} while (0)

// recurrent: 2 gates (1 compacted entry x 2 batches); wfr carries idx in low bits
#define GATEE(acf, wfr, vv) do { \
  union { float f; __half2 h; } _a; _a.f = (acf); \
  float2 ac = __half22float2(_a.h); \
  float ga = __builtin_amdgcn_rcpf(1.f + __builtin_amdgcn_exp2f(fmaf(ac.x, (vv).x, ac.y))); \
  float gb = __builtin_amdgcn_rcpf(1.f + __builtin_amdgcn_exp2f(fmaf(ac.x, (vv).y, ac.y))); \
  n0 = fmaf((wfr), ga, n0); d0 = fmaf(__builtin_fabsf(wfr), ga, d0); \
  n1 = fmaf((wfr), gb, n1); d1 = fmaf(__builtin_fabsf(wfr), gb, d1); \
} while (0)

// async global->LDS, 16 B per lane
__device__ __forceinline__ void gll16(const float4* g, float4* l) {
  __builtin_amdgcn_global_load_lds(
      (const __attribute__((address_space(1))) void*)g,
      (__attribute__((address_space(3))) void*)l, 16, 0, 0);
}

// issue one 2-chunk group (f4-rows 2g, 2g+1) into ring slot g&3
#define ISSUE_GRP(g) do { \
  gll16(Pb + (2 * (g) + 0) * NN, sb + (((g) & 3) * 2 + 0) * 64); \
  gll16(Pb + (2 * (g) + 1) * NN, sb + (((g) & 3) * 2 + 1) * 64); \
} while (0)

// one block = 2 batches x all 256 columns, all unfolds; no cross-block deps.
// NEW vs R14: 512 threads (8 waves), 2-way i-split, LDS 77 KB -> 2 blocks/CU.
// Two barrier-decoupled blocks per CU fill each other's reduction bubbles.
__global__ __launch_bounds__(512, 2) void ltc_sparse(
    const float* __restrict__ x, const float* __restrict__ state,
    const float* __restrict__ gl, const float* __restrict__ rp,
    const float* __restrict__ cap,
    const float* __restrict__ ow, const float* __restrict__ ob,
    const float4* __restrict__ PC4, const float4* __restrict__ SQ,
    const int* __restrict__ kmaxp, float* __restrict__ out) {
  extern __shared__ float4 lds4[];
  float4* stage = lds4;                  // 8w x 4slot x 2chunk x 64 = 4096 f4
  float2* vA2 = (float2*)(stage + 4096); // 256 f2 (128 f4)
  float2* vB2 = vA2 + 256;               // 128 f4
  float4* xt  = (float4*)(vB2 + 256);    // 64 f4
  float4* red = xt + 64;                 // 256 f4 (split-1 partials)
  float2* snd2 = (float2*)(red + 256);   // [2][256] f2 = 256 f4

  int tid = threadIdx.x;
  int j = tid & 255;
  int split = tid >> 8;                  // 0/1
  int wv = tid >> 6;                     // 0..7
  int lane = tid & 63;
  int jbase = (wv & 3) * 64;
  int bbase = blockIdx.x * 2;
  float4* sb = stage + wv * 512;
  int km = *kmaxp;                       // uniform; multiple of 16
  int G = km >> 3;                       // groups per split (4 entries/group)
  const float4* Pb = PC4 + (size_t)(split * (km >> 2)) * NN + jbase + lane;

  {
    int b = split, i = j;                // all 512 threads: one v element
    ((float*)vA2)[i * 2 + b] = state[(bbase + b) * NN + i];
    if (tid < 256) {
      int bx = tid >> 7, s = tid & 127;
      ((float*)xt)[(s >> 1) * 4 + (s & 1) * 2 + bx] = x[(bbase + bx) * SS + s];
    }
  }
  __syncthreads();

  // ---- sensory aggregation (dense; compiler-managed loads) ----
  {
    float n0 = 0, n1 = 0, d0 = 0, d1 = 0;
    const float4* Sp = SQ + split * 32 * NN + j;
    const float4* xq = xt + split * 32;
#pragma unroll
    for (int c = 0; c < 32; ++c) { float4 pq = Sp[c * NN]; float4 vv = xq[c]; GATE4(pq, vv); }
    if (split) red[j] = make_float4(n0, n1, d0, d1);
    __syncthreads();
    if (!split) {
      float4 r = red[j];
      snd2[j]       = make_float2(n0 + r.x, d0 + r.z);
      snd2[256 + j] = make_float2(n1 + r.y, d1 + r.w);
    }
    __syncthreads();
  }

  float cmt = cap[j] * (float)UNFOLDS;
  float glv = gl[j];
  float base_ = glv * rp[j];

  // ---- 6 unfolds, v ping-pongs in LDS; params DMA-staged per wave ----
  for (int u = 0; u < UNFOLDS; ++u) {
    const float2* vt2 = (u & 1) ? vB2 : vA2;
    float* vnf = (float*)((u & 1) ? vA2 : vB2);
    float n0 = 0, n1 = 0, d0 = 0, d1 = 0;

    auto body = [&](int g) {
      const float4* ps = sb + (g & 3) * 128;
      float4 pq0 = ps[lane];
      float4 pq1 = ps[64 + lane];
      float2 va0 = vt2[__float_as_uint(pq0.y) & 0xFF];
      float2 va1 = vt2[__float_as_uint(pq0.w) & 0xFF];
      float2 va2 = vt2[__float_as_uint(pq1.y) & 0xFF];
      float2 va3 = vt2[__float_as_uint(pq1.w) & 0xFF];
      GATEE(pq0.x, pq0.y, va0);
      GATEE(pq0.z, pq0.w, va1);
      GATEE(pq1.x, pq1.y, va2);
      GATEE(pq1.z, pq1.w, va3);
    };

    ISSUE_GRP(0); ISSUE_GRP(1); ISSUE_GRP(2); ISSUE_GRP(3);
    for (int g = 0; g < G - 4; ++g) {
      asm volatile("s_waitcnt vmcnt(6)" ::: "memory");
      body(g);
      ISSUE_GRP(g + 4);
    }
    asm volatile("s_waitcnt vmcnt(6)" ::: "memory"); body(G - 4);
    asm volatile("s_waitcnt vmcnt(4)" ::: "memory"); body(G - 3);
    asm volatile("s_waitcnt vmcnt(2)" ::: "memory"); body(G - 2);
    asm volatile("s_waitcnt vmcnt(0)" ::: "memory"); body(G - 1);

    if (split) red[j] = make_float4(n0, n1, d0, d1);
    __syncthreads();
    if (!split) {
      float4 r = red[j];
      float2 s0 = snd2[j], s1 = snd2[256 + j];
      float N0 = n0 + r.x + s0.x, D0 = d0 + r.z + s0.y;
      float N1 = n1 + r.y + s1.x, D1 = d1 + r.w + s1.y;
      float2 vj2 = ((const float2*)vt2)[j];
      float vn0 = (fmaf(cmt, vj2.x, base_) + N0) * __builtin_amdgcn_rcpf(cmt + glv + D0 + EPS_);
      float vn1 = (fmaf(cmt, vj2.y, base_) + N1) * __builtin_amdgcn_rcpf(cmt + glv + D1 + EPS_);
      vnf[j * 2 + 0] = vn0;
      vnf[j * 2 + 1] = vn1;
      if (u == UNFOLDS - 1) {
        out[BB * MM + (bbase + 0) * NN + j] = vn0;
        out[BB * MM + (bbase + 1) * NN + j] = vn1;
        if (j < MM) {
          out[(bbase + 0) * MM + j] = fmaf(vn0, ow[j], ob[j]);
          out[(bbase + 1) * MM + j] = fmaf(vn1, ow[j], ob[j]);
        }
      }
    }
    __syncthreads();
  }
}

extern "C" void kernel_launch(void* const* d_in, const int* in_sizes, int n_in,
                              void* d_out, int out_size, void* d_ws, size_t ws_size,
                              hipStream_t stream) {
  const float* x     = (const float*)d_in[0];
  const float* state = (const float*)d_in[1];
  const float* gl    = (const float*)d_in[2];
  const float* rp    = (const float*)d_in[3];
  const float* cap   = (const float*)d_in[4];
  const float* w     = (const float*)d_in[5];
  const float* sg    = (const float*)d_in[6];
  const float* mu    = (const float*)d_in[7];
  const float* E     = (const float*)d_in[8];
  const float* sw    = (const float*)d_in[9];
  const float* ssg   = (const float*)d_in[10];
  const float* smu   = (const float*)d_in[11];
  const float* sE    = (const float*)d_in[12];
  const float* mask  = (const float*)d_in[13];
  const float* smask = (const float*)d_in[14];
  const float* iw    = (const float*)d_in[15];
  const float* ib    = (const float*)d_in[16];
  const float* ow    = (const float*)d_in[17];
  const float* ob    = (const float*)d_in[18];

  float4* PC4 = (float4*)d_ws;                 // [128][NN] f4 = 512 KiB
  float4* SQ  = PC4 + 128 * NN;                // [SS/2][NN] f4 = 256 KiB
  int* cnt    = (int*)(SQ + (SS / 2) * NN);    // 256 ints
  int* kmax   = cnt + 256;
  float* fout = (float*)d_out;                 // [B*M out][B*N v]

  // LDS: stage 4096 + v 256 + xt 64 + red 256 + snd2 256 = 4928 f4 = 78848 B
  // <= 80 KiB -> 2 blocks/CU
  const int smem = 4928 * 16;
  hipFuncSetAttribute((const void*)ltc_sparse,
                      hipFuncAttributeMaxDynamicSharedMemorySize, smem);

  prep_compact<<<256 + (SS * NN) / 256, 256, 0, stream>>>(
      w, sg, mu, E, mask, sw, ssg, smu, sE, smask, iw, ib,
      (float2*)PC4, cnt, SQ);
  prep_kmax<<<1, 256, 0, stream>>>(cnt, kmax);
  ltc_sparse<<<BB / 2, 512, smem, stream>>>(
      x, state, gl, rp, cap, ow, ob, PC4, SQ, kmax, fout);
}

// Round 17
// 56.358 us; speedup vs baseline: 1.0810x; 1.0810x over previous
//
#include <hip/hip_runtime.h>
#include <hip/hip_fp16.h>

#define BB 512
#define NN 256
#define SS 128
#define MM 64
#define UNFOLDS 6

static constexpr float EPS_ = 1e-8f;
static constexpr float L2E = 1.4426950408889634f;

// ---- prep A (blocks 0..255): column-compact recurrent params, column j=bid ----
// entry (r,j): float2 { bitcast(half2{a,c}), wE with source-idx in low 8 mantissa bits }
// packed pairwise into float4 rows PC4[r>>1][j]; rows >= cnt zeroed.
// ---- prep A (blocks 256..383): dense sensory pack (SQ format) ----
__global__ __launch_bounds__(256) void prep_compact(
    const float* __restrict__ w, const float* __restrict__ sg,
    const float* __restrict__ mu, const float* __restrict__ E,
    const float* __restrict__ mask,
    const float* __restrict__ sw, const float* __restrict__ ssg,
    const float* __restrict__ smu, const float* __restrict__ sE,
    const float* __restrict__ smask,
    const float* __restrict__ iw, const float* __restrict__ ib,
    float2* __restrict__ PC2, int* __restrict__ cnt, float4* __restrict__ SQ) {
  int bid = blockIdx.x;
  int t = threadIdx.x;
  if (bid < 256) {
    int j = bid;
    int lane = t & 63, wvi = t >> 6;
    __shared__ int wtot[4];
    int g = t * NN + j;
    float m = mask[g];
    bool active = (m != 0.0f);
    float a = sg[g] * L2E;
    union { __half2 h; float f; } ac;
    ac.h = __floats2half2_rn(-a, a * mu[g]);
    float wE = w[g] * m * E[g];
    unsigned uw = (__float_as_uint(wE) & 0xFFFFFF00u) | (unsigned)t;
    unsigned long long bal = __ballot(active);
    if (lane == 63) wtot[wvi] = __popcll(bal);
    __syncthreads();
    int base = 0;
    for (int k = 0; k < wvi; ++k) base += wtot[k];
    int total = wtot[0] + wtot[1] + wtot[2] + wtot[3];
    if (active) {
      int r = base + __popcll(bal & ((1ull << lane) - 1ull));
      PC2[((r >> 1) * NN + j) * 2 + (r & 1)] = make_float2(ac.f, __uint_as_float(uw));
    }
    int zr = total + t;
    if (zr < 256) PC2[((zr >> 1) * NN + j) * 2 + (zr & 1)] = make_float2(0.f, 0.f);
    if (t == 0) cnt[j] = total;
  } else {
    int e = (bid - 256) * 256 + t;       // < SS*NN
    int s = e >> 8, j = e & 255;
    float a = ssg[e] * L2E;
    union { __half2 h; float f; } u_;
    u_.h = __floats2half2_rn(-a * iw[s], a * (smu[e] - ib[s]));
    float wE = sw[e] * smask[e] * sE[e];
    float* dst = (float*)(SQ + (s >> 1) * NN + j);
    dst[(s & 1) * 2 + 0] = u_.f;
    dst[(s & 1) * 2 + 1] = wE;
  }
}

// max over cnt, padded to multiple of 16
__global__ __launch_bounds__(256) void prep_kmax(const int* __restrict__ cnt,
                                                 int* __restrict__ kmax) {
  __shared__ int red[256];
  int t = threadIdx.x;
  red[t] = cnt[t];
  __syncthreads();
  for (int s2 = 128; s2 > 0; s2 >>= 1) {
    if (t < s2) red[t] = max(red[t], red[t + s2]);
    __syncthreads();
  }
  if (t == 0) *kmax = (red[0] + 15) & ~15;
}

// sensory: 4 gates from one float4 (2 entries, f32 wE) + float4 of x
#define GATE4(pq, vv) do { \
  union { float f; __half2 h; } _u0, _u1; \
  _u0.f = (pq).x; _u1.f = (pq).z; \
  float2 ac0 = __half22float2(_u0.h); \
  float2 ac1 = __half22float2(_u1.h); \
  float g0a = __builtin_amdgcn_rcpf(1.f + __builtin_amdgcn_exp2f(fmaf(ac0.x, (vv).x, ac0.y))); \
  float g0b = __builtin_amdgcn_rcpf(1.f + __builtin_amdgcn_exp2f(fmaf(ac0.x, (vv).y, ac0.y))); \
  float g1a = __builtin_amdgcn_rcpf(1.f + __builtin_amdgcn_exp2f(fmaf(ac1.x, (vv).z, ac1.y))); \
  float g1b = __builtin_amdgcn_rcpf(1.f + __builtin_amdgcn_exp2f(fmaf(ac1.x, (vv).w, ac1.y))); \
  n0 = fmaf((pq).y, g0a, n0); d0 = fmaf(__builtin_fabsf((pq).y), g0a, d0); \
  n1 = fmaf((pq).y, g0b, n1); d1 = fmaf(__builtin_fabsf((pq).y), g0b, d1); \
  n0 = fmaf((pq).w, g1a, n0); d0 = fmaf(__builtin_fabsf((pq).w), g1a, d0); \
  n1 = fmaf((pq).w, g1b, n1); d1 = fmaf(__builtin_fabsf((pq).w), g1b, d1); \
} while (0)

// recurrent: 2 gates (1 compacted entry x 2 batches); wfr carries idx in low bits
#define GATEE(acf, wfr, vv) do { \
  union { float f; __half2 h; } _a; _a.f = (acf); \
  float2 ac = __half22float2(_a.h); \
  float ga = __builtin_amdgcn_rcpf(1.f + __builtin_amdgcn_exp2f(fmaf(ac.x, (vv).x, ac.y))); \
  float gb = __builtin_amdgcn_rcpf(1.f + __builtin_amdgcn_exp2f(fmaf(ac.x, (vv).y, ac.y))); \
  n0 = fmaf((wfr), ga, n0); d0 = fmaf(__builtin_fabsf(wfr), ga, d0); \
  n1 = fmaf((wfr), gb, n1); d1 = fmaf(__builtin_fabsf(wfr), gb, d1); \
} while (0)

// async global->LDS, 16 B per lane
__device__ __forceinline__ void gll16(const float4* g, float4* l) {
  __builtin_amdgcn_global_load_lds(
      (const __attribute__((address_space(1))) void*)g,
      (__attribute__((address_space(3))) void*)l, 16, 0, 0);
}

// issue one 2-chunk group (f4-rows 2g, 2g+1) into ring slot g&3
#define ISSUE_GRP(g) do { \
  gll16(Pb + (2 * (g) + 0) * NN, sb + (((g) & 3) * 2 + 0) * 64); \
  gll16(Pb + (2 * (g) + 1) * NN, sb + (((g) & 3) * 2 + 1) * 64); \
} while (0)

// load group params (slot) + v gathers into named regs (LDS software pipeline)
#define LOADP(slot, B0, B1, U0, U1, U2, U3) do { \
  const float4* _ps = sb + (slot) * 128; \
  B0 = _ps[lane]; B1 = _ps[64 + lane]; \
  U0 = vt2[__float_as_uint(B0.y) & 0xFF]; \
  U1 = vt2[__float_as_uint(B0.w) & 0xFF]; \
  U2 = vt2[__float_as_uint(B1.y) & 0xFF]; \
  U3 = vt2[__float_as_uint(B1.w) & 0xFF]; \
} while (0)

#define COMP4() do { \
  GATEE(A0.x, A0.y, W0); GATEE(A0.z, A0.w, W1); \
  GATEE(A1.x, A1.y, W2); GATEE(A1.z, A1.w, W3); \
} while (0)

#define SHIFT() do { A0 = B0; A1 = B1; W0 = U0; W1 = U1; W2 = U2; W3 = U3; } while (0)

// one block = 2 batches x all 256 columns, all unfolds; no cross-block deps.
// R15 structure (1024 thr, 4-way split, wave-private DMA ring) + NEW:
// one-body-ahead LDS software pipeline -- iteration g loads group g+1's
// params+gathers into registers, then computes group g (hides ~240 cy of
// serial ds_read chain under ~230 cy of trans-heavy compute).
__global__ __launch_bounds__(1024, 4) void ltc_sparse(
    const float* __restrict__ x, const float* __restrict__ state,
    const float* __restrict__ gl, const float* __restrict__ rp,
    const float* __restrict__ cap,
    const float* __restrict__ ow, const float* __restrict__ ob,
    const float4* __restrict__ PC4, const float4* __restrict__ SQ,
    const int* __restrict__ kmaxp, float* __restrict__ out) {
  extern __shared__ float4 lds4[];
  float4* stage = lds4;                  // 16w x 4slot x 2chunk x 64 = 8192 f4
  float2* vA2 = (float2*)(stage + 8192); // 256 f2 (128 f4)
  float2* vB2 = vA2 + 256;               // 128 f4
  float4* xt  = (float4*)(vB2 + 256);    // 64 f4
  float4* red = xt + 64;                 // 1024 f4
  float2* snd2 = (float2*)(red + 1024);  // [2][256] f2 = 256 f4

  int tid = threadIdx.x;
  int j = tid & 255;
  int split = tid >> 8;
  int wv = tid >> 6;
  int lane = tid & 63;
  int jbase = (wv & 3) * 64;
  int bbase = blockIdx.x * 2;
  float4* sb = stage + wv * 512;
  int km = *kmaxp;                       // uniform; multiple of 16 (~160)
  int G = km >> 4;                       // groups per split (4 entries/group)
  const float4* Pb = PC4 + (size_t)(split * (km >> 3)) * NN + jbase + lane;

  if (tid < 512) {
    int b = tid >> 8, i = tid & 255;
    ((float*)vA2)[i * 2 + b] = state[(bbase + b) * NN + i];
  } else if (tid < 768) {
    int t = tid - 512, b = t >> 7, s = t & 127;
    ((float*)xt)[(s >> 1) * 4 + (s & 1) * 2 + b] = x[(bbase + b) * SS + s];
  }
  __syncthreads();

  // ring prologue for unfold 0 -- latency hides under the sensory phase
  ISSUE_GRP(0); ISSUE_GRP(1); ISSUE_GRP(2); ISSUE_GRP(3);

  // ---- sensory aggregation (dense; compiler-managed loads) ----
  {
    float n0 = 0, n1 = 0, d0 = 0, d1 = 0;
    const float4* Sp = SQ + split * 16 * NN + j;
    const float4* xq = xt + split * 16;
#pragma unroll
    for (int c = 0; c < 16; ++c) { float4 pq = Sp[c * NN]; float4 vv = xq[c]; GATE4(pq, vv); }
    red[split * 256 + j] = make_float4(n0, n1, d0, d1);
    __syncthreads();
    if (split < 2) {
      float n = 0, dd = 0;
#pragma unroll
      for (int k = 0; k < 4; ++k) {
        float4 r = red[k * 256 + j];
        n += split ? r.y : r.x; dd += split ? r.w : r.z;
      }
      snd2[split * 256 + j] = make_float2(n, dd);
    }
    __syncthreads();
  }

  float cmt = cap[j] * (float)UNFOLDS;
  float glv = gl[j];
  float base_ = glv * rp[j];

  // ---- 6 unfolds; LDS-pipelined body loop ----
  for (int u = 0; u < UNFOLDS; ++u) {
    const float2* vt2 = (u & 1) ? vB2 : vA2;
    float* vnf = (float*)((u & 1) ? vA2 : vB2);
    float n0 = 0, n1 = 0, d0 = 0, d1 = 0;

    float4 A0, A1; float2 W0, W1, W2, W3;
    // preamble: group 0 into pipeline regs
    asm volatile("s_waitcnt vmcnt(6)" ::: "memory");
    LOADP(0, A0, A1, W0, W1, W2, W3);
    // main: load g+1, compute g, issue g+4
    for (int g = 0; g < G - 4; ++g) {
      float4 B0, B1; float2 U0, U1, U2, U3;
      asm volatile("s_waitcnt vmcnt(4)" ::: "memory");
      LOADP((g + 1) & 3, B0, B1, U0, U1, U2, U3);
      COMP4();
      ISSUE_GRP(g + 4);
      SHIFT();
    }
    // epilogue: 3 pipelined drains + final compute
    {
      float4 B0, B1; float2 U0, U1, U2, U3;
      asm volatile("s_waitcnt vmcnt(4)" ::: "memory");
      LOADP((G - 3) & 3, B0, B1, U0, U1, U2, U3); COMP4(); SHIFT();
      asm volatile("s_waitcnt vmcnt(2)" ::: "memory");
      LOADP((G - 2) & 3, B0, B1, U0, U1, U2, U3); COMP4(); SHIFT();
      asm volatile("s_waitcnt vmcnt(0)" ::: "memory");
      LOADP((G - 1) & 3, B0, B1, U0, U1, U2, U3); COMP4(); SHIFT();
      COMP4();
    }
    // next unfold's ring prologue -- flies across the reduction barriers
    if (u < UNFOLDS - 1) { ISSUE_GRP(0); ISSUE_GRP(1); ISSUE_GRP(2); ISSUE_GRP(3); }

    red[split * 256 + j] = make_float4(n0, n1, d0, d1);
    asm volatile("s_waitcnt lgkmcnt(0)" ::: "memory");   // LDS visibility only
    __builtin_amdgcn_s_barrier();                        // DMA stays in flight
    if (split < 2) {
      int b = split;
      float2 sj = snd2[b * 256 + j];
      float N = sj.x, D = sj.y;
#pragma unroll
      for (int k = 0; k < 4; ++k) {
        float4 r = red[k * 256 + j];
        N += b ? r.y : r.x; D += b ? r.w : r.z;
      }
      float2 vj2 = ((const float2*)vt2)[j];
      float vj = b ? vj2.y : vj2.x;
      float vn = (fmaf(cmt, vj, base_) + N) * __builtin_amdgcn_rcpf(cmt + glv + D + EPS_);
      vnf[j * 2 + b] = vn;
      if (u == UNFOLDS - 1) {
        out[BB * MM + (bbase + b) * NN + j] = vn;
        if (j < MM) out[(bbase + b) * MM + j] = fmaf(vn, ow[j], ob[j]);
      }
    }
    asm volatile("s_waitcnt lgkmcnt(0)" ::: "memory");
    __builtin_amdgcn_s_barrier();
  }
}

extern "C" void kernel_launch(void* const* d_in, const int* in_sizes, int n_in,
                              void* d_out, int out_size, void* d_ws, size_t ws_size,
                              hipStream_t stream) {
  const float* x     = (const float*)d_in[0];
  const float* state = (const float*)d_in[1];
  const float* gl    = (const float*)d_in[2];
  const float* rp    = (const float*)d_in[3];
  const float* cap   = (const float*)d_in[4];
  const float* w     = (const float*)d_in[5];
  const float* sg    = (const float*)d_in[6];
  const float* mu    = (const float*)d_in[7];
  const float* E     = (const float*)d_in[8];
  const float* sw    = (const float*)d_in[9];
  const float* ssg   = (const float*)d_in[10];
  const float* smu   = (const float*)d_in[11];
  const float* sE    = (const float*)d_in[12];
  const float* mask  = (const float*)d_in[13];
  const float* smask = (const float*)d_in[14];
  const float* iw    = (const float*)d_in[15];
  const float* ib    = (const float*)d_in[16];
  const float* ow    = (const float*)d_in[17];
  const float* ob    = (const float*)d_in[18];

  float4* PC4 = (float4*)d_ws;                 // [128][NN] f4 = 512 KiB
  float4* SQ  = PC4 + 128 * NN;                // [SS/2][NN] f4 = 256 KiB
  int* cnt    = (int*)(SQ + (SS / 2) * NN);    // 256 ints
  int* kmax   = cnt + 256;
  float* fout = (float*)d_out;                 // [B*M out][B*N v]

  // LDS: stage 8192 + v 256 + xt 64 + red 1024 + snd2 256 = 9792 f4
  const int smem = 9792 * 16;                  // 156672 B <= 163840 B
  hipFuncSetAttribute((const void*)ltc_sparse,
                      hipFuncAttributeMaxDynamicSharedMemorySize, smem);

  prep_compact<<<256 + (SS * NN) / 256, 256, 0, stream>>>(
      w, sg, mu, E, mask, sw, ssg, smu, sE, smask, iw, ib,
      (float2*)PC4, cnt, SQ);
  prep_kmax<<<1, 256, 0, stream>>>(cnt, kmax);
  ltc_sparse<<<BB / 2, 1024, smem, stream>>>(
      x, state, gl, rp, cap, ow, ob, PC4, SQ, kmax, fout);
}